// Round 1
// baseline (892.561 us; speedup 1.0000x reference)
//
#include <hip/hip_runtime.h>
#include <hip/hip_bf16.h>

typedef __hip_bfloat16 bf16;
typedef __bf16 bf16x8 __attribute__((ext_vector_type(8)));
typedef float f32x4 __attribute__((ext_vector_type(4)));
typedef short short8 __attribute__((ext_vector_type(8)));

#define NH 24
#define NKV 8
#define HD 128
#define SEQ 2048
#define NREP 3

__device__ inline void gload16(const void* g, void* l) {
  __builtin_amdgcn_global_load_lds(
      (const __attribute__((address_space(1))) void*)g,
      (__attribute__((address_space(3))) void*)l, 16, 0, 0);
}

// ---------------- cast f32 -> bf16 (vectorized) ----------------
__global__ void cast_f32_bf16(const float* __restrict__ in, bf16* __restrict__ out, int n4) {
  int i = blockIdx.x * 256 + threadIdx.x;
  if (i >= n4) return;
  float4 v = reinterpret_cast<const float4*>(in)[i];
  ushort4 u;
  u.x = __builtin_bit_cast(unsigned short, __float2bfloat16(v.x));
  u.y = __builtin_bit_cast(unsigned short, __float2bfloat16(v.y));
  u.z = __builtin_bit_cast(unsigned short, __float2bfloat16(v.z));
  u.w = __builtin_bit_cast(unsigned short, __float2bfloat16(v.w));
  reinterpret_cast<ushort4*>(out)[i] = u;
}

// ---------------- transpose + cast: W (KxN f32, row-major) -> WT (NxK bf16) ----------------
__global__ void transpose_cast(const float* __restrict__ W, bf16* __restrict__ WT, int K, int N) {
  __shared__ bf16 tile[32][33];
  int n0 = blockIdx.x * 32, k0 = blockIdx.y * 32;
  int tx = threadIdx.x, ty = threadIdx.y;  // (32, 8)
#pragma unroll
  for (int i = 0; i < 4; ++i) {
    int kl = ty + i * 8;
    tile[kl][tx] = __float2bfloat16(W[(size_t)(k0 + kl) * N + n0 + tx]);
  }
  __syncthreads();
#pragma unroll
  for (int i = 0; i < 4; ++i) {
    int nl = ty + i * 8;
    WT[(size_t)(n0 + nl) * K + k0 + tx] = tile[tx][nl];
  }
}

// ---------------- RoPE in-place on bf16 buffer (rows x H x 128) ----------------
__global__ void rope_kernel(bf16* __restrict__ T, const float* __restrict__ cosT,
                            const float* __restrict__ sinT, int H, int total) {
  int i = blockIdx.x * 256 + threadIdx.x;
  if (i >= total) return;
  int d2 = i & 63;
  int rh = i >> 6;            // r*H + h
  int r = rh / H;             // r = b*SEQ + s
  int s = r & (SEQ - 1);
  float c = cosT[s * 64 + d2];
  float sn = sinT[s * 64 + d2];
  bf16* p = T + (size_t)rh * HD + d2 * 2;
  float a = __bfloat162float(p[0]);
  float b = __bfloat162float(p[1]);
  p[0] = __float2bfloat16(a * c - b * sn);
  p[1] = __float2bfloat16(a * sn + b * c);
}

// ---------------- GEMM: C[M,N] = A[M,K] @ BT[N,K]^T  (m97-style, 128x128 tile) ----------------
template <bool OUT_BF16>
__global__ __launch_bounds__(256) void gemm_bt(const bf16* __restrict__ A,
                                               const bf16* __restrict__ BT,
                                               void* __restrict__ Cv,
                                               int M, int N, int K) {
  __shared__ bf16 lsA[128 * 32];
  __shared__ bf16 lsB[128 * 32];
  int m0 = blockIdx.y * 128, n0 = blockIdx.x * 128;
  int tid = threadIdx.x;
  int w = tid >> 6, lane = tid & 63;
  int wm = w >> 1, wn = w & 1;
  int lr = lane & 15, lk = lane >> 4;
  f32x4 acc[4][4] = {};
  for (int k0 = 0; k0 < K; k0 += 32) {
    __syncthreads();
#pragma unroll
    for (int is = 0; is < 2; ++is) {
      int slot = is * 256 + tid;
      int row = slot >> 2, kc = slot & 3;
      gload16(A + (size_t)(m0 + row) * K + k0 + kc * 8, lsA + slot * 8);
      gload16(BT + (size_t)(n0 + row) * K + k0 + kc * 8, lsB + slot * 8);
    }
    __syncthreads();
    bf16x8 aF[4], bF[4];
#pragma unroll
    for (int t = 0; t < 4; ++t) {
      aF[t] = *reinterpret_cast<const bf16x8*>(&lsA[(wm * 64 + t * 16 + lr) * 32 + lk * 8]);
      bF[t] = *reinterpret_cast<const bf16x8*>(&lsB[(wn * 64 + t * 16 + lr) * 32 + lk * 8]);
    }
#pragma unroll
    for (int mt = 0; mt < 4; ++mt)
#pragma unroll
      for (int nt = 0; nt < 4; ++nt)
        acc[mt][nt] = __builtin_amdgcn_mfma_f32_16x16x32_bf16(aF[mt], bF[nt], acc[mt][nt], 0, 0, 0);
  }
#pragma unroll
  for (int mt = 0; mt < 4; ++mt)
#pragma unroll
    for (int nt = 0; nt < 4; ++nt)
#pragma unroll
      for (int r = 0; r < 4; ++r) {
        int m = m0 + wm * 64 + mt * 16 + lk * 4 + r;
        int n = n0 + wn * 64 + nt * 16 + lr;
        float v = acc[mt][nt][r];
        if (OUT_BF16)
          reinterpret_cast<bf16*>(Cv)[(size_t)m * N + n] = __float2bfloat16(v);
        else
          reinterpret_cast<float*>(Cv)[(size_t)m * N + n] = v;
      }
}

// ---------------- Flash attention (causal, GQA) ----------------
// Q: (4096, 24*128) bf16 ; K,V: (4096, 8*128) bf16 ; O: (4096, 24*128) bf16
__global__ __launch_bounds__(256) void attn_kernel(const bf16* __restrict__ Q,
                                                   const bf16* __restrict__ K,
                                                   const bf16* __restrict__ V,
                                                   bf16* __restrict__ O) {
  __shared__ bf16 Kt[32 * 136];     // K tile, rows padded 128->136
  __shared__ bf16 Vt[128 * 40];     // V tile transposed: [d][r], rows padded 32->40
  __shared__ bf16 Pb[4][16 * 40];   // per-wave P buffer, rows padded 32->40
  int qt = blockIdx.x;
  int bh = blockIdx.y;
  int b = bh / NH, h = bh % NH, g = h / NREP;
  int tid = threadIdx.x, w = tid >> 6, lane = tid & 63;
  int lr = lane & 15, lk = lane >> 4;
  int q0 = qt * 64 + w * 16;

  // Q fragments (A operand), rows q0+lr, d = kk*32 + lk*8 + j
  bf16x8 aQ[4];
  const bf16* qptr = Q + (size_t)(b * SEQ + q0 + lr) * (NH * HD) + h * HD;
#pragma unroll
  for (int kk = 0; kk < 4; ++kk)
    aQ[kk] = *reinterpret_cast<const bf16x8*>(qptr + kk * 32 + lk * 8);

  f32x4 Oacc[8] = {};
  float m_s[4], l_s[4];
#pragma unroll
  for (int r = 0; r < 4; ++r) { m_s[r] = -1e30f; l_s[r] = 0.f; }
  const float scale = 0.08838834764831845f;  // 1/sqrt(128)

  int jmax = qt * 64 + 63;
  for (int j0 = 0; j0 <= jmax; j0 += 32) {
    __syncthreads();
    // stage K tile (row-major, padded)
    {
      int r = tid >> 3, c0 = (tid & 7) * 16;
      const bf16* src = K + ((size_t)(b * SEQ + j0 + r) * NKV + g) * HD + c0;
      *reinterpret_cast<short8*>(&Kt[r * 136 + c0]) = *reinterpret_cast<const short8*>(src);
      *reinterpret_cast<short8*>(&Kt[r * 136 + c0 + 8]) = *reinterpret_cast<const short8*>(src + 8);
    }
    // stage V transposed: Vt[d][r]
    for (int i = tid; i < 32 * 128; i += 256) {
      int r = i >> 7, d = i & 127;
      Vt[d * 40 + r] = V[((size_t)(b * SEQ + j0 + r) * NKV + g) * HD + d];
    }
    __syncthreads();
    if (j0 > q0 + 15) continue;  // wave-level causal skip (no barriers below)

    // scores: S = Q @ K^T -> two 16x16 tiles (cols j0..j0+15, j0+16..j0+31)
    f32x4 s0 = {0.f, 0.f, 0.f, 0.f}, s1 = {0.f, 0.f, 0.f, 0.f};
#pragma unroll
    for (int kk = 0; kk < 4; ++kk) {
      bf16x8 b0 = *reinterpret_cast<const bf16x8*>(&Kt[lr * 136 + kk * 32 + lk * 8]);
      bf16x8 b1 = *reinterpret_cast<const bf16x8*>(&Kt[(lr + 16) * 136 + kk * 32 + lk * 8]);
      s0 = __builtin_amdgcn_mfma_f32_16x16x32_bf16(aQ[kk], b0, s0, 0, 0, 0);
      s1 = __builtin_amdgcn_mfma_f32_16x16x32_bf16(aQ[kk], b1, s1, 0, 0, 0);
    }
    // mask + online softmax. D rows: q0 + lk*4 + r ; cols: j0+lr, j0+16+lr
    int kc0 = j0 + lr, kc1 = j0 + 16 + lr;
    float sv0[4], sv1[4], mx[4];
#pragma unroll
    for (int r = 0; r < 4; ++r) {
      int qrow = q0 + lk * 4 + r;
      sv0[r] = (kc0 > qrow) ? -1e30f : s0[r] * scale;
      sv1[r] = (kc1 > qrow) ? -1e30f : s1[r] * scale;
      mx[r] = fmaxf(sv0[r], sv1[r]);
    }
#pragma unroll
    for (int d = 1; d < 16; d <<= 1)
#pragma unroll
      for (int r = 0; r < 4; ++r) mx[r] = fmaxf(mx[r], __shfl_xor(mx[r], d, 64));
    float alpha[4], p0[4], p1[4], rs[4];
#pragma unroll
    for (int r = 0; r < 4; ++r) {
      float mn = fmaxf(m_s[r], mx[r]);
      alpha[r] = expf(m_s[r] - mn);
      m_s[r] = mn;
      int qrow = q0 + lk * 4 + r;
      p0[r] = (kc0 > qrow) ? 0.f : expf(sv0[r] - mn);
      p1[r] = (kc1 > qrow) ? 0.f : expf(sv1[r] - mn);
      rs[r] = p0[r] + p1[r];
    }
#pragma unroll
    for (int d = 1; d < 16; d <<= 1)
#pragma unroll
      for (int r = 0; r < 4; ++r) rs[r] += __shfl_xor(rs[r], d, 64);
#pragma unroll
    for (int r = 0; r < 4; ++r) l_s[r] = l_s[r] * alpha[r] + rs[r];
#pragma unroll
    for (int nc = 0; nc < 8; ++nc)
#pragma unroll
      for (int r = 0; r < 4; ++r) Oacc[nc][r] *= alpha[r];
    // P -> LDS (wave-private), then re-read as A fragments
    bf16* pb = Pb[w];
#pragma unroll
    for (int r = 0; r < 4; ++r) {
      pb[(lk * 4 + r) * 40 + lr] = __float2bfloat16(p0[r]);
      pb[(lk * 4 + r) * 40 + 16 + lr] = __float2bfloat16(p1[r]);
    }
    asm volatile("s_waitcnt lgkmcnt(0)" ::: "memory");
    bf16x8 aP = *reinterpret_cast<const bf16x8*>(&pb[lr * 40 + lk * 8]);
    // O += P @ V
#pragma unroll
    for (int nc = 0; nc < 8; ++nc) {
      bf16x8 bV = *reinterpret_cast<const bf16x8*>(&Vt[(nc * 16 + lr) * 40 + lk * 8]);
      Oacc[nc] = __builtin_amdgcn_mfma_f32_16x16x32_bf16(aP, bV, Oacc[nc], 0, 0, 0);
    }
  }
  // epilogue: O /= l, store bf16
#pragma unroll
  for (int nc = 0; nc < 8; ++nc)
#pragma unroll
    for (int r = 0; r < 4; ++r) {
      float v = Oacc[nc][r] / l_s[r];
      O[(size_t)(b * SEQ + q0 + lk * 4 + r) * (NH * HD) + h * HD + nc * 16 + lr] =
          __float2bfloat16(v);
    }
}

extern "C" void kernel_launch(void* const* d_in, const int* in_sizes, int n_in,
                              void* d_out, int out_size, void* d_ws, size_t ws_size,
                              hipStream_t stream) {
  const float* x = (const float*)d_in[0];
  const float* wq = (const float*)d_in[1];
  const float* wk = (const float*)d_in[2];
  const float* wv = (const float*)d_in[3];
  const float* wo = (const float*)d_in[4];
  const float* fc = (const float*)d_in[5];
  const float* fs = (const float*)d_in[6];
  float* out = (float*)d_out;
  (void)in_sizes; (void)n_in; (void)out_size; (void)ws_size;

  const int R = 2 * SEQ;        // 4096 rows
  const int DIMc = 3072;
  const int NQ = NH * HD;       // 3072
  const int NKd = NKV * HD;     // 1024

  char* ws = (char*)d_ws;
  bf16* xb = (bf16*)ws;   ws += (size_t)R * DIMc * 2;
  bf16* wqT = (bf16*)ws;  ws += (size_t)NQ * DIMc * 2;
  bf16* wkT = (bf16*)ws;  ws += (size_t)NKd * DIMc * 2;
  bf16* wvT = (bf16*)ws;  ws += (size_t)NKd * DIMc * 2;
  bf16* woT = (bf16*)ws;  ws += (size_t)DIMc * NQ * 2;
  bf16* Qb = (bf16*)ws;   ws += (size_t)R * NQ * 2;
  bf16* Kb = (bf16*)ws;   ws += (size_t)R * NKd * 2;
  bf16* Vb = (bf16*)ws;   ws += (size_t)R * NKd * 2;
  bf16* Ob = (bf16*)ws;   ws += (size_t)R * NQ * 2;

  // 1) cast x to bf16
  {
    int n4 = R * DIMc / 4;
    cast_f32_bf16<<<n4 / 256, 256, 0, stream>>>(x, xb, n4);
  }
  // 2) transpose+cast weights to N x K bf16
  transpose_cast<<<dim3(NQ / 32, DIMc / 32), dim3(32, 8), 0, stream>>>(wq, wqT, DIMc, NQ);
  transpose_cast<<<dim3(NKd / 32, DIMc / 32), dim3(32, 8), 0, stream>>>(wk, wkT, DIMc, NKd);
  transpose_cast<<<dim3(NKd / 32, DIMc / 32), dim3(32, 8), 0, stream>>>(wv, wvT, DIMc, NKd);
  transpose_cast<<<dim3(DIMc / 32, NQ / 32), dim3(32, 8), 0, stream>>>(wo, woT, NQ, DIMc);
  // 3) QKV projections
  gemm_bt<true><<<dim3(NQ / 128, R / 128), 256, 0, stream>>>(xb, wqT, Qb, R, NQ, DIMc);
  gemm_bt<true><<<dim3(NKd / 128, R / 128), 256, 0, stream>>>(xb, wkT, Kb, R, NKd, DIMc);
  gemm_bt<true><<<dim3(NKd / 128, R / 128), 256, 0, stream>>>(xb, wvT, Vb, R, NKd, DIMc);
  // 4) RoPE on Q and K
  {
    int totQ = R * NH * 64;
    rope_kernel<<<totQ / 256, 256, 0, stream>>>(Qb, fc, fs, NH, totQ);
    int totK = R * NKV * 64;
    rope_kernel<<<totK / 256, 256, 0, stream>>>(Kb, fc, fs, NKV, totK);
  }
  // 5) attention
  attn_kernel<<<dim3(SEQ / 64, 2 * NH), 256, 0, stream>>>(Qb, Kb, Vb, Ob);
  // 6) output projection -> f32 out
  gemm_bt<false><<<dim3(DIMc / 128, R / 128), 256, 0, stream>>>(Ob, woT, out, R, DIMc, NQ);
}

// Round 3
// 656.137 us; speedup vs baseline: 1.3603x; 1.3603x over previous
//
#include <hip/hip_runtime.h>
#include <hip/hip_bf16.h>

typedef __hip_bfloat16 bf16;
typedef __bf16 bf16x8 __attribute__((ext_vector_type(8)));
typedef float f32x4 __attribute__((ext_vector_type(4)));
typedef short short8 __attribute__((ext_vector_type(8)));

#define NH 24
#define NKV 8
#define HD 128
#define SEQ 2048
#define NREP 3

__device__ inline void gload16(const void* g, void* l) {
  __builtin_amdgcn_global_load_lds(
      (const __attribute__((address_space(1))) void*)g,
      (__attribute__((address_space(3))) void*)l, 16, 0, 0);
}

// ---------------- cast f32 -> bf16 (vectorized) ----------------
__global__ void cast_f32_bf16(const float* __restrict__ in, bf16* __restrict__ out, int n4) {
  int i = blockIdx.x * 256 + threadIdx.x;
  if (i >= n4) return;
  float4 v = reinterpret_cast<const float4*>(in)[i];
  ushort4 u;
  u.x = __builtin_bit_cast(unsigned short, __float2bfloat16(v.x));
  u.y = __builtin_bit_cast(unsigned short, __float2bfloat16(v.y));
  u.z = __builtin_bit_cast(unsigned short, __float2bfloat16(v.z));
  u.w = __builtin_bit_cast(unsigned short, __float2bfloat16(v.w));
  reinterpret_cast<ushort4*>(out)[i] = u;
}

// ---------------- transpose + cast: W (KxN f32) -> WT (NxK bf16) ----------------
__global__ void transpose_cast(const float* __restrict__ W, bf16* __restrict__ WT, int K, int N) {
  __shared__ bf16 tile[32][33];
  int n0 = blockIdx.x * 32, k0 = blockIdx.y * 32;
  int tx = threadIdx.x, ty = threadIdx.y;  // (32, 8)
#pragma unroll
  for (int i = 0; i < 4; ++i) {
    int kl = ty + i * 8;
    tile[kl][tx] = __float2bfloat16(W[(size_t)(k0 + kl) * N + n0 + tx]);
  }
  __syncthreads();
#pragma unroll
  for (int i = 0; i < 4; ++i) {
    int nl = ty + i * 8;
    WT[(size_t)(n0 + nl) * K + k0 + tx] = tile[tx][nl];
  }
}

// ---------------- V global transpose: Vb (b*S rows, g*HD cols) -> Vt[b][g][d][s] ----------------
__global__ void transpose_v(const bf16* __restrict__ Vb, bf16* __restrict__ Vt) {
  __shared__ bf16 tile[32][33];
  int bg = blockIdx.z;
  int b = bg >> 3, g = bg & 7;
  int s0 = blockIdx.x * 32, d0 = blockIdx.y * 32;
  int tx = threadIdx.x, ty = threadIdx.y;  // (32, 8)
#pragma unroll
  for (int i = 0; i < 4; ++i) {
    int sl = ty + i * 8;
    tile[sl][tx] = Vb[(size_t)(b * SEQ + s0 + sl) * (NKV * HD) + g * HD + d0 + tx];
  }
  __syncthreads();
#pragma unroll
  for (int i = 0; i < 4; ++i) {
    int dl = ty + i * 8;
    Vt[((size_t)(b * NKV + g) * HD + d0 + dl) * SEQ + s0 + tx] = tile[tx][dl];
  }
}

// ---------------- RoPE in-place on bf16 buffer ----------------
__global__ void rope_kernel(bf16* __restrict__ T, const float* __restrict__ cosT,
                            const float* __restrict__ sinT, int H, int total) {
  int i = blockIdx.x * 256 + threadIdx.x;
  if (i >= total) return;
  int d2 = i & 63;
  int rh = i >> 6;
  int r = rh / H;
  int s = r & (SEQ - 1);
  float c = cosT[s * 64 + d2];
  float sn = sinT[s * 64 + d2];
  bf16* p = T + (size_t)rh * HD + d2 * 2;
  float a = __bfloat162float(p[0]);
  float b = __bfloat162float(p[1]);
  p[0] = __float2bfloat16(a * c - b * sn);
  p[1] = __float2bfloat16(a * sn + b * c);
}

// ---------------- GEMM: C[M,N] = A[M,K] @ BT[N,K]^T  (m97-style) ----------------
template <bool OUT_BF16>
__global__ __launch_bounds__(256) void gemm_bt(const bf16* __restrict__ A,
                                               const bf16* __restrict__ BT,
                                               void* __restrict__ Cv,
                                               int M, int N, int K) {
  __shared__ bf16 lsA[128 * 32];
  __shared__ bf16 lsB[128 * 32];
  int m0 = blockIdx.y * 128, n0 = blockIdx.x * 128;
  int tid = threadIdx.x;
  int w = tid >> 6, lane = tid & 63;
  int wm = w >> 1, wn = w & 1;
  int lr = lane & 15, lk = lane >> 4;
  f32x4 acc[4][4] = {};
  for (int k0 = 0; k0 < K; k0 += 32) {
    __syncthreads();
#pragma unroll
    for (int is = 0; is < 2; ++is) {
      int slot = is * 256 + tid;
      int row = slot >> 2, kc = slot & 3;
      gload16(A + (size_t)(m0 + row) * K + k0 + kc * 8, lsA + slot * 8);
      gload16(BT + (size_t)(n0 + row) * K + k0 + kc * 8, lsB + slot * 8);
    }
    __syncthreads();
    bf16x8 aF[4], bF[4];
#pragma unroll
    for (int t = 0; t < 4; ++t) {
      aF[t] = *reinterpret_cast<const bf16x8*>(&lsA[(wm * 64 + t * 16 + lr) * 32 + lk * 8]);
      bF[t] = *reinterpret_cast<const bf16x8*>(&lsB[(wn * 64 + t * 16 + lr) * 32 + lk * 8]);
    }
#pragma unroll
    for (int mt = 0; mt < 4; ++mt)
#pragma unroll
      for (int nt = 0; nt < 4; ++nt)
        acc[mt][nt] = __builtin_amdgcn_mfma_f32_16x16x32_bf16(aF[mt], bF[nt], acc[mt][nt], 0, 0, 0);
  }
#pragma unroll
  for (int mt = 0; mt < 4; ++mt)
#pragma unroll
    for (int nt = 0; nt < 4; ++nt)
#pragma unroll
      for (int r = 0; r < 4; ++r) {
        int m = m0 + wm * 64 + mt * 16 + lk * 4 + r;
        int n = n0 + wn * 64 + nt * 16 + lr;
        float v = acc[mt][nt][r];
        if (OUT_BF16)
          reinterpret_cast<bf16*>(Cv)[(size_t)m * N + n] = __float2bfloat16(v);
        else
          reinterpret_cast<float*>(Cv)[(size_t)m * N + n] = v;
      }
}

// ---------------- Flash attention (causal, GQA) ----------------
// 4 waves x 16 q-rows = 64 q-rows/block; KV tile = 64 rows.
// Klds: [64 s][16 chunks of 8 bf16], chunk XOR-swizzled by (s&7)  (both-sides swizzle)
// Vlds: [128 d][8 chunks of 8 bf16 (s)], chunk XOR-swizzled by (d&7)
// Plds: per-wave [16 q][8 chunks of 8 bf16 (k)], chunk XOR-swizzled by (q&7)
#define SCALE_LOG2 0.12751745f  // (1/sqrt(128)) * log2(e)

__global__ __launch_bounds__(256, 3) void attn_kernel(const bf16* __restrict__ Q,
                                                      const bf16* __restrict__ K,
                                                      const bf16* __restrict__ Vt,
                                                      bf16* __restrict__ O) {
  __shared__ bf16 Klds[64 * 128];      // 16 KB
  __shared__ bf16 Vlds[128 * 64];      // 16 KB
  __shared__ bf16 Plds[4][16 * 64];    // 8 KB
  int qt = (int)gridDim.x - 1 - (int)blockIdx.x;   // big-work blocks first
  int bh = blockIdx.y;
  int b = bh / NH, h = bh % NH, g = h / NREP;
  int tid = threadIdx.x, w = tid >> 6, lane = tid & 63;
  int lr = lane & 15, lk = lane >> 4;
  int q0 = qt * 64 + w * 16;  // wave's q base

  // --- Q fragments (A operand): rows q0+lr, k = kk*32 + lk*8 + j ---
  bf16x8 aQ[4];
  {
    const bf16* qrow = Q + ((size_t)(b * SEQ) + q0 + lr) * (NH * HD) + h * HD;
#pragma unroll
    for (int kk = 0; kk < 4; ++kk)
      aQ[kk] = *reinterpret_cast<const bf16x8*>(qrow + kk * 32 + lk * 8);
  }

  // --- staging offsets (j0-independent) ---
  const bf16* kvK = K + ((size_t)b * SEQ * NKV + g) * HD;
  const bf16* kvVt = Vt + ((size_t)(b * NKV + g) * HD) * SEQ;
  int koff[4];
  bf16* kdst[4];
#pragma unroll
  for (int i = 0; i < 4; ++i) {
    int t = i * 256 + tid;          // 1024 K slots of 8 bf16
    int row = t >> 4, c = t & 15;
    int sc = c ^ (row & 7);         // pre-swizzled source chunk
    koff[i] = row * (NKV * HD) + sc * 8;
    kdst[i] = Klds + t * 8;
  }
  int voff[4];
  bf16* vdst[4];
#pragma unroll
  for (int i = 0; i < 4; ++i) {
    int t = i * 256 + tid;          // 1024 V slots of 8 bf16
    int d = t >> 3, c = t & 7;
    int sc = c ^ (d & 7);
    voff[i] = d * SEQ + sc * 8;
    vdst[i] = Vlds + t * 8;
  }

  f32x4 Oacc[8] = {};
  float m_s[4], l_s[4];
#pragma unroll
  for (int r = 0; r < 4; ++r) { m_s[r] = -1e30f; l_s[r] = 0.f; }

  bf16* pb = Plds[w];

  int jmax = qt * 64 + 63;
  for (int j0 = 0; j0 <= jmax; j0 += 64) {
    __syncthreads();  // prev-tile readers done
    {
      const bf16* ks = kvK + (size_t)j0 * (NKV * HD);
      const bf16* vs = kvVt + j0;
#pragma unroll
      for (int i = 0; i < 4; ++i) gload16(ks + koff[i], kdst[i]);
#pragma unroll
      for (int i = 0; i < 4; ++i) gload16(vs + voff[i], vdst[i]);
    }
    __syncthreads();  // staging complete (barrier drains vmcnt)
    if (j0 > q0 + 15) continue;

    // ---- QK^T : 4 n-tiles of 16 cols ----
    f32x4 sc4[4] = {};
#pragma unroll
    for (int kk = 0; kk < 4; ++kk) {
#pragma unroll
      for (int nt = 0; nt < 4; ++nt) {
        int jrow = nt * 16 + lr;
        int pos = (4 * kk + lk) ^ (lr & 7);
        bf16x8 bK = *reinterpret_cast<const bf16x8*>(&Klds[jrow * 128 + pos * 8]);
        sc4[nt] = __builtin_amdgcn_mfma_f32_16x16x32_bf16(aQ[kk], bK, sc4[nt], 0, 0, 0);
      }
    }

    // ---- mask + online softmax (log2 domain) ----
    float sv[4][4], mx[4];
#pragma unroll
    for (int r = 0; r < 4; ++r) mx[r] = -3e38f;
#pragma unroll
    for (int nt = 0; nt < 4; ++nt) {
      int col = j0 + nt * 16 + lr;
#pragma unroll
      for (int r = 0; r < 4; ++r) {
        int row = q0 + lk * 4 + r;
        sv[nt][r] = (col > row) ? -3e38f : sc4[nt][r] * SCALE_LOG2;
        mx[r] = fmaxf(mx[r], sv[nt][r]);
      }
    }
#pragma unroll
    for (int d = 1; d < 16; d <<= 1)
#pragma unroll
      for (int r = 0; r < 4; ++r) mx[r] = fmaxf(mx[r], __shfl_xor(mx[r], d, 64));
    float alpha[4], rs[4];
    float p[4][4];
#pragma unroll
    for (int r = 0; r < 4; ++r) {
      float mn = fmaxf(m_s[r], mx[r]);
      alpha[r] = exp2f(m_s[r] - mn);
      m_s[r] = mn;
      rs[r] = 0.f;
#pragma unroll
      for (int nt = 0; nt < 4; ++nt) {
        p[nt][r] = exp2f(sv[nt][r] - mn);
        rs[r] += p[nt][r];
      }
    }
#pragma unroll
    for (int d = 1; d < 16; d <<= 1)
#pragma unroll
      for (int r = 0; r < 4; ++r) rs[r] += __shfl_xor(rs[r], d, 64);
#pragma unroll
    for (int r = 0; r < 4; ++r) l_s[r] = l_s[r] * alpha[r] + rs[r];
#pragma unroll
    for (int nc = 0; nc < 8; ++nc)
#pragma unroll
      for (int r = 0; r < 4; ++r) Oacc[nc][r] *= alpha[r];

    // ---- P -> wave-private swizzled LDS ----
#pragma unroll
    for (int nt = 0; nt < 4; ++nt)
#pragma unroll
      for (int r = 0; r < 4; ++r) {
        int row = lk * 4 + r;
        int c = nt * 16 + lr;
        pb[row * 64 + (((c >> 3) ^ (row & 7)) * 8) + (c & 7)] = __float2bfloat16(p[nt][r]);
      }
    asm volatile("s_waitcnt lgkmcnt(0)" ::: "memory");
    __builtin_amdgcn_sched_barrier(0);

    // ---- O += P @ V  (V fragments: contiguous bf16x8 along s from Vlds) ----
#pragma unroll
    for (int kb = 0; kb < 2; ++kb) {
      int px = ((kb * 4 + lk) ^ (lr & 7)) * 8;
      bf16x8 aP = *reinterpret_cast<const bf16x8*>(&pb[lr * 64 + px]);
#pragma unroll
      for (int nc = 0; nc < 8; ++nc) {
        bf16x8 bV = *reinterpret_cast<const bf16x8*>(&Vlds[(nc * 16 + lr) * 64 + px]);
        Oacc[nc] = __builtin_amdgcn_mfma_f32_16x16x32_bf16(aP, bV, Oacc[nc], 0, 0, 0);
      }
    }
  }

  // ---- epilogue ----
#pragma unroll
  for (int r = 0; r < 4; ++r) {
    float inv = 1.0f / l_s[r];
    size_t rowoff = ((size_t)(b * SEQ) + q0 + lk * 4 + r) * (NH * HD) + h * HD;
#pragma unroll
    for (int nc = 0; nc < 8; ++nc)
      O[rowoff + nc * 16 + lr] = __float2bfloat16(Oacc[nc][r] * inv);
  }
}

extern "C" void kernel_launch(void* const* d_in, const int* in_sizes, int n_in,
                              void* d_out, int out_size, void* d_ws, size_t ws_size,
                              hipStream_t stream) {
  const float* x = (const float*)d_in[0];
  const float* wq = (const float*)d_in[1];
  const float* wk = (const float*)d_in[2];
  const float* wv = (const float*)d_in[3];
  const float* wo = (const float*)d_in[4];
  const float* fc = (const float*)d_in[5];
  const float* fs = (const float*)d_in[6];
  float* out = (float*)d_out;
  (void)in_sizes; (void)n_in; (void)out_size; (void)ws_size;

  const int R = 2 * SEQ;
  const int DIMc = 3072;
  const int NQ = NH * HD;
  const int NKd = NKV * HD;

  char* ws = (char*)d_ws;
  bf16* xb = (bf16*)ws;   ws += (size_t)R * DIMc * 2;
  bf16* wqT = (bf16*)ws;  ws += (size_t)NQ * DIMc * 2;
  bf16* wkT = (bf16*)ws;  ws += (size_t)NKd * DIMc * 2;
  bf16* wvT = (bf16*)ws;  ws += (size_t)NKd * DIMc * 2;
  bf16* woT = (bf16*)ws;  ws += (size_t)DIMc * NQ * 2;
  bf16* Qb = (bf16*)ws;   ws += (size_t)R * NQ * 2;
  bf16* Kb = (bf16*)ws;   ws += (size_t)R * NKd * 2;
  bf16* Vb = (bf16*)ws;   ws += (size_t)R * NKd * 2;
  bf16* Ob = (bf16*)ws;   ws += (size_t)R * NQ * 2;
  bf16* VtG = xb;  // aliases xb: xb is dead after the V projection GEMM

  {
    int n4 = R * DIMc / 4;
    cast_f32_bf16<<<n4 / 256, 256, 0, stream>>>(x, xb, n4);
  }
  transpose_cast<<<dim3(NQ / 32, DIMc / 32), dim3(32, 8), 0, stream>>>(wq, wqT, DIMc, NQ);
  transpose_cast<<<dim3(NKd / 32, DIMc / 32), dim3(32, 8), 0, stream>>>(wk, wkT, DIMc, NKd);
  transpose_cast<<<dim3(NKd / 32, DIMc / 32), dim3(32, 8), 0, stream>>>(wv, wvT, DIMc, NKd);
  transpose_cast<<<dim3(DIMc / 32, NQ / 32), dim3(32, 8), 0, stream>>>(wo, woT, NQ, DIMc);
  gemm_bt<true><<<dim3(NQ / 128, R / 128), 256, 0, stream>>>(xb, wqT, Qb, R, NQ, DIMc);
  gemm_bt<true><<<dim3(NKd / 128, R / 128), 256, 0, stream>>>(xb, wkT, Kb, R, NKd, DIMc);
  gemm_bt<true><<<dim3(NKd / 128, R / 128), 256, 0, stream>>>(xb, wvT, Vb, R, NKd, DIMc);
  // V -> Vt[b][g][d][s]  (xb region; xb no longer needed)
  transpose_v<<<dim3(SEQ / 32, HD / 32, 2 * NKV), dim3(32, 8), 0, stream>>>(Vb, VtG);
  {
    int totQ = R * NH * 64;
    rope_kernel<<<totQ / 256, 256, 0, stream>>>(Qb, fc, fs, NH, totQ);
    int totK = R * NKV * 64;
    rope_kernel<<<totK / 256, 256, 0, stream>>>(Kb, fc, fs, NKV, totK);
  }
  attn_kernel<<<dim3(SEQ / 64, 2 * NH), 256, 0, stream>>>(Qb, Kb, VtG, Ob);
  gemm_bt<false><<<dim3(DIMc / 128, R / 128), 256, 0, stream>>>(Ob, woT, out, R, DIMc, NQ);
}